// Round 2
// baseline (368.484 us; speedup 1.0000x reference)
//
#include <hip/hip_runtime.h>

#define IMG_H 1024
#define IMG_W 1024
#define NBATCH 8
#define NCH 3
#define NPIX (IMG_H * IMG_W)
#define SEGS 64                         // 32 row-bands x 2 column-halves per batch
#define NTOT (8388608LL)                // 8 * 1024 * 1024

// 3-level radix select on the f32 bit pattern of g (g >= 0 -> bits monotone)
#define BINS1 4096                      // bits >> 19
#define SH1 19
#define BINS2 4096                      // (bits >> 7) & 4095
#define SH2 7
#define BINS3 128                       // bits & 127

// ---- workspace layout (bytes) ----
#define WS_HIST2_OFF   0
#define WS_HIST2_BYTES (2 * NBATCH * BINS2 * 4)        // 256 KB (zeroed)
#define WS_HIST3_OFF   (WS_HIST2_OFF + WS_HIST2_BYTES)
#define WS_HIST3_BYTES (2 * NBATCH * BINS3 * 4)        // 8 KB (zeroed)
#define WS_MISC_OFF    (WS_HIST3_OFF + WS_HIST3_BYTES)
#define WS_MISC_BYTES  4096                            // zeroed
#define WS_H1R_OFF     (WS_MISC_OFF + WS_MISC_BYTES)
#define WS_H1R_BYTES   (2 * NBATCH * BINS1 * 4)        // 256 KB
#define WS_H1P_OFF     (WS_H1R_OFF + WS_H1R_BYTES)
#define WS_H1P_BYTES   (2 * NBATCH * SEGS * BINS1 * 2) // 8 MB
#define WS_TOTAL       (WS_H1P_OFF + WS_H1P_BYTES)
#define WS_ZERO_BYTES  (WS_HIST2_BYTES + WS_HIST3_BYTES + WS_MISC_BYTES)

struct Row3f { float l, c, r; };

__device__ __forceinline__ Row3f load3(const float* __restrict__ img, int y, int x) {
    Row3f o;
    if ((unsigned)y >= (unsigned)IMG_H) { o.l = o.c = o.r = 0.0f; return o; }
    const float* row = img + (size_t)y * IMG_W;
    o.c = row[x];
    o.l = (x > 0)         ? row[x - 1] : 0.0f;
    o.r = (x < IMG_W - 1) ? row[x + 1] : 0.0f;
    return o;
}

// f32 Sobel with row-major sequential tap accumulation (matches Eigen/np einsum
// order; products by +-1,+-2 are exact so fma-contraction cannot change results).
// KX=[[-1,0,1],[-2,0,2],[-1,0,1]], KY=[[1,2,1],[0,0,0],[-1,-2,-1]] (cross-corr).
__device__ __forceinline__ float sobel_g(const Row3f& r0, const Row3f& r1, const Row3f& r2) {
    float gx = r0.r - r0.l;       // fl(-x00 + x02)
    gx -= 2.0f * r1.l;
    gx += 2.0f * r1.r;
    gx -= r2.l;
    gx += r2.r;
    float gy = r0.l + 2.0f * r0.c;
    gy += r0.r;
    gy -= r2.l;
    gy -= 2.0f * r2.c;
    gy -= r2.r;
    return fabsf(gx) + fabsf(gy);  // sum over |channel| axis: one f32 add
}

// ---------------- pass 0: loss + level-1 histograms ----------------
extern "C" __global__ __launch_bounds__(512)
void k_pass0(const float* __restrict__ A, const float* __restrict__ B,
             const float* __restrict__ F,
             unsigned short* __restrict__ hist1p, double* __restrict__ lossAcc)
{
    __shared__ unsigned int h[2 * BINS1];               // 32 KB: [A | B]
    __shared__ double lsum[8];
    const int t = threadIdx.x;
    for (int i = t; i < 2 * BINS1; i += 512) h[i] = 0u;
    __syncthreads();

    const int blk = blockIdx.x;                         // 512 = 8 batches * 64 segs
    const int batch = blk >> 6;
    const int seg = blk & 63;
    const int y0 = (seg >> 1) * 32;
    const int x  = (seg & 1) * 512 + t;

    const float* a = A + (size_t)batch * NCH * NPIX;    // channel 0
    const float* b = B + (size_t)batch * NCH * NPIX;
    const float* f = F + (size_t)batch * NCH * NPIX;

    Row3f a0 = load3(a, y0 - 1, x), a1 = load3(a, y0, x), a2;
    Row3f b0 = load3(b, y0 - 1, x), b1 = load3(b, y0, x), b2;
    Row3f f0 = load3(f, y0 - 1, x), f1 = load3(f, y0, x), f2;

    double loss = 0.0;
    for (int i = 0; i < 32; ++i) {
        const int y = y0 + i;
        a2 = load3(a, y + 1, x);
        b2 = load3(b, y + 1, x);
        f2 = load3(f, y + 1, x);
        const float gA = sobel_g(a0, a1, a2);
        const float gB = sobel_g(b0, b1, b2);
        const float gF = sobel_g(f0, f1, f2);
        atomicAdd(&h[__float_as_uint(gA) >> SH1], 1u);
        atomicAdd(&h[BINS1 + (__float_as_uint(gB) >> SH1)], 1u);
        const float jm = fmaxf(gA, gB);
        loss += (double)fabsf(gF - jm);
        a0 = a1; a1 = a2;
        b0 = b1; b1 = b2;
        f0 = f1; f1 = f2;
    }
    __syncthreads();

    unsigned short* oA = hist1p + ((size_t)batch            * SEGS + seg) * BINS1;
    unsigned short* oB = hist1p + ((size_t)(NBATCH + batch) * SEGS + seg) * BINS1;
    for (int i = t; i < BINS1; i += 512) {              // per-block counts <= 16384 -> u16
        oA[i] = (unsigned short)h[i];
        oB[i] = (unsigned short)h[BINS1 + i];
    }

    for (int off = 32; off > 0; off >>= 1) loss += __shfl_down(loss, off);
    if ((t & 63) == 0) lsum[t >> 6] = loss;
    __syncthreads();
    if (t == 0) {
        double s = 0.0;
        for (int i = 0; i < 8; ++i) s += lsum[i];
        atomicAdd(lossAcc, s);
    }
}

// ---------------- scan1a: reduce per-seg hists ----------------
extern "C" __global__ __launch_bounds__(256)
void k_scan1a(const unsigned short* __restrict__ hist1p, unsigned int* __restrict__ hist1r)
{
    const int idx = blockIdx.x * 256 + threadIdx.x;     // 65536 = 16 * 4096
    const int ib  = idx >> 12;
    const int bin = idx & (BINS1 - 1);
    const unsigned short* p = hist1p + (size_t)ib * SEGS * BINS1 + bin;
    unsigned int s = 0;
    #pragma unroll 8
    for (int sg = 0; sg < SEGS; ++sg) s += p[(size_t)sg * BINS1];
    hist1r[idx] = s;
}

// ---------------- scan1b: level-1 bin + residual rank ----------------
extern "C" __global__ __launch_bounds__(256)
void k_scan1b(const unsigned int* __restrict__ hist1r, const int* __restrict__ kptr,
              int* __restrict__ sel1, int* __restrict__ resid1)
{
    const int ib = blockIdx.x, t = threadIdx.x;
    const unsigned int* hr = hist1r + (size_t)ib * BINS1;
    __shared__ unsigned int csum[256];
    unsigned int s = 0;
    for (int j = 0; j < BINS1 / 256; ++j) s += hr[t * (BINS1 / 256) + j];
    csum[t] = s;
    __syncthreads();
    if (t == 0) {
        long long k = (long long)kptr[0];               // 1-indexed kth smallest
        if (k < 1 || k > (long long)NPIX) {             // defensive: scalar sent as f32?
            float kf = ((const float*)kptr)[0];
            k = (long long)kf;
            if (k < 1) k = 1;
            if (k > NPIX) k = NPIX;
        }
        long long cum = 0;
        int c = 0;
        while (c < 255 && cum + csum[c] < k) { cum += csum[c]; ++c; }
        int bin = c * (BINS1 / 256);
        while (bin < BINS1 - 1 && cum + hr[bin] < k) { cum += hr[bin]; ++bin; }
        sel1[ib] = bin;
        resid1[ib] = (int)(k - cum);
    }
}

// ---------------- pass B: level-2 sparse histogram ----------------
extern "C" __global__ __launch_bounds__(512)
void k_passB(const float* __restrict__ A, const float* __restrict__ B,
             const int* __restrict__ sel1, unsigned int* __restrict__ hist2)
{
    const int t = threadIdx.x;
    const int blk = blockIdx.x;
    const int batch = blk >> 6;
    const int seg = blk & 63;
    const int y0 = (seg >> 1) * 32;
    const int x  = (seg & 1) * 512 + t;

    const float* a = A + (size_t)batch * NCH * NPIX;
    const float* b = B + (size_t)batch * NCH * NPIX;
    const unsigned sA = (unsigned)sel1[batch];
    const unsigned sB = (unsigned)sel1[NBATCH + batch];
    unsigned int* h2A = hist2 + (size_t)batch * BINS2;
    unsigned int* h2B = hist2 + (size_t)(NBATCH + batch) * BINS2;

    Row3f a0 = load3(a, y0 - 1, x), a1 = load3(a, y0, x), a2;
    Row3f b0 = load3(b, y0 - 1, x), b1 = load3(b, y0, x), b2;
    for (int i = 0; i < 32; ++i) {
        const int y = y0 + i;
        a2 = load3(a, y + 1, x);
        b2 = load3(b, y + 1, x);
        const unsigned uA = __float_as_uint(sobel_g(a0, a1, a2));
        const unsigned uB = __float_as_uint(sobel_g(b0, b1, b2));
        if ((uA >> SH1) == sA) atomicAdd(&h2A[(uA >> SH2) & (BINS2 - 1)], 1u);
        if ((uB >> SH1) == sB) atomicAdd(&h2B[(uB >> SH2) & (BINS2 - 1)], 1u);
        a0 = a1; a1 = a2;
        b0 = b1; b1 = b2;
    }
}

// ---------------- scan2b: level-2 bin + residual rank ----------------
extern "C" __global__ __launch_bounds__(256)
void k_scan2b(const unsigned int* __restrict__ hist2, const int* __restrict__ resid1,
              int* __restrict__ sel2, int* __restrict__ resid2)
{
    const int ib = blockIdx.x, t = threadIdx.x;
    const unsigned int* h2 = hist2 + (size_t)ib * BINS2;
    __shared__ unsigned int csum[256];
    unsigned int s = 0;
    for (int j = 0; j < BINS2 / 256; ++j) s += h2[t * (BINS2 / 256) + j];
    csum[t] = s;
    __syncthreads();
    if (t == 0) {
        long long k = (long long)resid1[ib];
        long long cum = 0;
        int c = 0;
        while (c < 255 && cum + csum[c] < k) { cum += csum[c]; ++c; }
        int bin = c * (BINS2 / 256);
        while (bin < BINS2 - 1 && cum + h2[bin] < k) { cum += h2[bin]; ++bin; }
        sel2[ib] = bin;
        resid2[ib] = (int)(k - cum);
    }
}

// ---------------- pass C: level-3 sparse histogram ----------------
extern "C" __global__ __launch_bounds__(512)
void k_passC(const float* __restrict__ A, const float* __restrict__ B,
             const int* __restrict__ sel1, const int* __restrict__ sel2,
             unsigned int* __restrict__ hist3)
{
    const int t = threadIdx.x;
    const int blk = blockIdx.x;
    const int batch = blk >> 6;
    const int seg = blk & 63;
    const int y0 = (seg >> 1) * 32;
    const int x  = (seg & 1) * 512 + t;

    const float* a = A + (size_t)batch * NCH * NPIX;
    const float* b = B + (size_t)batch * NCH * NPIX;
    const unsigned pA = ((unsigned)sel1[batch] << 12)          | (unsigned)sel2[batch];
    const unsigned pB = ((unsigned)sel1[NBATCH + batch] << 12) | (unsigned)sel2[NBATCH + batch];
    unsigned int* h3A = hist3 + (size_t)batch * BINS3;
    unsigned int* h3B = hist3 + (size_t)(NBATCH + batch) * BINS3;

    Row3f a0 = load3(a, y0 - 1, x), a1 = load3(a, y0, x), a2;
    Row3f b0 = load3(b, y0 - 1, x), b1 = load3(b, y0, x), b2;
    for (int i = 0; i < 32; ++i) {
        const int y = y0 + i;
        a2 = load3(a, y + 1, x);
        b2 = load3(b, y + 1, x);
        const unsigned uA = __float_as_uint(sobel_g(a0, a1, a2));
        const unsigned uB = __float_as_uint(sobel_g(b0, b1, b2));
        if ((uA >> SH2) == pA) atomicAdd(&h3A[uA & (BINS3 - 1)], 1u);
        if ((uB >> SH2) == pB) atomicAdd(&h3B[uB & (BINS3 - 1)], 1u);
        a0 = a1; a1 = a2;
        b0 = b1; b1 = b2;
    }
}

// ---------------- scan3: kth bits + loss write ----------------
extern "C" __global__ __launch_bounds__(64)
void k_scan3(const unsigned int* __restrict__ hist3, const int* __restrict__ sel1,
             const int* __restrict__ sel2, const int* __restrict__ resid2,
             unsigned int* __restrict__ kthbits,
             const double* __restrict__ lossAcc, float* __restrict__ out)
{
    const int ib = blockIdx.x, t = threadIdx.x;
    if (t == 0) {
        const unsigned int* h3 = hist3 + (size_t)ib * BINS3;
        long long k = (long long)resid2[ib];
        long long cum = 0;
        int bin = 0;
        while (bin < BINS3 - 1 && cum + h3[bin] < k) { cum += h3[bin]; ++bin; }
        kthbits[ib] = ((unsigned)sel1[ib] << SH1) | ((unsigned)sel2[ib] << SH2) | (unsigned)bin;
    }
    if (ib == 0 && t == 63) {
        out[0] = (float)(lossAcc[0] * (1.0 / 8388608.0));
    }
}

// ---------------- pass D: masks ----------------
extern "C" __global__ __launch_bounds__(512)
void k_passD(const float* __restrict__ A, const float* __restrict__ B,
             const unsigned int* __restrict__ kthbits, float* __restrict__ out)
{
    const int t = threadIdx.x;
    const int blk = blockIdx.x;
    const int batch = blk >> 6;
    const int seg = blk & 63;
    const int y0 = (seg >> 1) * 32;
    const int x  = (seg & 1) * 512 + t;

    const float* a = A + (size_t)batch * NCH * NPIX;
    const float* b = B + (size_t)batch * NCH * NPIX;
    const unsigned kA = kthbits[batch];
    const unsigned kB = kthbits[NBATCH + batch];
    float* mA = out + 1 + (size_t)batch * NPIX;
    float* mB = out + 1 + (size_t)NTOT + (size_t)batch * NPIX;

    Row3f a0 = load3(a, y0 - 1, x), a1 = load3(a, y0, x), a2;
    Row3f b0 = load3(b, y0 - 1, x), b1 = load3(b, y0, x), b2;
    for (int i = 0; i < 32; ++i) {
        const int y = y0 + i;
        a2 = load3(a, y + 1, x);
        b2 = load3(b, y + 1, x);
        const unsigned uA = __float_as_uint(sobel_g(a0, a1, a2));
        const unsigned uB = __float_as_uint(sobel_g(b0, b1, b2));
        mA[(size_t)y * IMG_W + x] = (uA >= kA) ? 1.0f : 0.0f;
        mB[(size_t)y * IMG_W + x] = (uB >= kB) ? 1.0f : 0.0f;
        a0 = a1; a1 = a2;
        b0 = b1; b1 = b2;
    }
}

extern "C" void kernel_launch(void* const* d_in, const int* in_sizes, int n_in,
                              void* d_out, int out_size, void* d_ws, size_t ws_size,
                              hipStream_t stream)
{
    const float* A = (const float*)d_in[0];
    const float* B = (const float*)d_in[1];
    const float* F = (const float*)d_in[2];
    const int* kptr = (const int*)d_in[3];
    float* out = (float*)d_out;

    if (ws_size < (size_t)WS_TOTAL) return;             // need ~8.9 MB scratch

    char* ws = (char*)d_ws;
    unsigned int* hist2   = (unsigned int*)(ws + WS_HIST2_OFF);
    unsigned int* hist3   = (unsigned int*)(ws + WS_HIST3_OFF);
    double* lossAcc       = (double*)(ws + WS_MISC_OFF);
    int* sel1             = (int*)(ws + WS_MISC_OFF + 64);
    int* resid1           = (int*)(ws + WS_MISC_OFF + 128);
    int* sel2             = (int*)(ws + WS_MISC_OFF + 192);
    int* resid2           = (int*)(ws + WS_MISC_OFF + 256);
    unsigned int* kthbits = (unsigned int*)(ws + WS_MISC_OFF + 320);
    unsigned int* hist1r  = (unsigned int*)(ws + WS_H1R_OFF);
    unsigned short* hist1p = (unsigned short*)(ws + WS_H1P_OFF);

    hipMemsetAsync(ws, 0, WS_ZERO_BYTES, stream);       // accumulators zeroed

    k_pass0 <<<dim3(NBATCH * SEGS), dim3(512), 0, stream>>>(A, B, F, hist1p, lossAcc);
    k_scan1a<<<dim3(2 * NBATCH * BINS1 / 256), dim3(256), 0, stream>>>(hist1p, hist1r);
    k_scan1b<<<dim3(2 * NBATCH), dim3(256), 0, stream>>>(hist1r, kptr, sel1, resid1);
    k_passB <<<dim3(NBATCH * SEGS), dim3(512), 0, stream>>>(A, B, sel1, hist2);
    k_scan2b<<<dim3(2 * NBATCH), dim3(256), 0, stream>>>(hist2, resid1, sel2, resid2);
    k_passC <<<dim3(NBATCH * SEGS), dim3(512), 0, stream>>>(A, B, sel1, sel2, hist3);
    k_scan3 <<<dim3(2 * NBATCH), dim3(64), 0, stream>>>(hist3, sel1, sel2, resid2, kthbits, lossAcc, out);
    k_passD <<<dim3(NBATCH * SEGS), dim3(512), 0, stream>>>(A, B, kthbits, out);
}

// Round 3
// 344.784 us; speedup vs baseline: 1.0687x; 1.0687x over previous
//
#include <hip/hip_runtime.h>

#define IMG_H 1024
#define IMG_W 1024
#define NBATCH 8
#define NCH 3
#define NPIX (IMG_H * IMG_W)
#define SEGS 64                         // pass0: 32 row-bands x 2 column-halves per batch
#define NTOT (8388608LL)                // 8 * 1024 * 1024

#define BINS1 4096                      // level-1: bits >> 19
#define SH1 19

// ---- workspace layout (bytes) ----
#define WS_MISC_OFF   0                 // zeroed: lossAcc @0 (8B), gCnt[16] @64
#define WS_MISC_BYTES 4096
#define WS_H1R_OFF    (WS_MISC_OFF + WS_MISC_BYTES)
#define WS_H1R_BYTES  (2 * NBATCH * BINS1 * 4)         // 256 KB
#define WS_H1P_OFF    (WS_H1R_OFF + WS_H1R_BYTES)
#define WS_H1P_BYTES  (2 * NBATCH * SEGS * BINS1 * 2)  // 8 MB
#define WS_LIST_OFF   (WS_H1P_OFF + WS_H1P_BYTES)

struct Row3f { float l, c, r; };

__device__ __forceinline__ Row3f load3(const float* __restrict__ img, int y, int x) {
    Row3f o;
    if ((unsigned)y >= (unsigned)IMG_H) { o.l = o.c = o.r = 0.0f; return o; }
    const float* row = img + (size_t)y * IMG_W;
    o.c = row[x];
    o.l = (x > 0)         ? row[x - 1] : 0.0f;
    o.r = (x < IMG_W - 1) ? row[x + 1] : 0.0f;
    return o;
}

// BIT-EXACT vs reference: f32, row-major sequential tap order (verified round 2).
__device__ __forceinline__ float sobel_g(const Row3f& r0, const Row3f& r1, const Row3f& r2) {
    float gx = r0.r - r0.l;
    gx -= 2.0f * r1.l;
    gx += 2.0f * r1.r;
    gx -= r2.l;
    gx += r2.r;
    float gy = r0.l + 2.0f * r0.c;
    gy += r0.r;
    gy -= r2.l;
    gy -= 2.0f * r2.c;
    gy -= r2.r;
    return fabsf(gx) + fabsf(gy);
}

// ---------------- pass 0: loss + level-1 histograms (2 replicated copies) ----------------
extern "C" __global__ __launch_bounds__(512)
void k_pass0(const float* __restrict__ A, const float* __restrict__ B,
             const float* __restrict__ F,
             unsigned short* __restrict__ hist1p, double* __restrict__ lossAcc)
{
    __shared__ unsigned int h[4 * BINS1];   // 64 KB: copy0[A|B], copy1[A|B]
    __shared__ double lsum[8];
    const int t = threadIdx.x;
    for (int i = t; i < 4 * BINS1; i += 512) h[i] = 0u;
    __syncthreads();

    const int blk = blockIdx.x;             // 512 = 8 batches * 64 segs
    const int batch = blk >> 6;
    const int seg = blk & 63;
    const int y0 = (seg >> 1) * 32;
    const int x  = (seg & 1) * 512 + t;
    unsigned int* hc = h + (t >> 8) * (2 * BINS1);   // wave-half replicated copy

    const float* a = A + (size_t)batch * NCH * NPIX;
    const float* b = B + (size_t)batch * NCH * NPIX;
    const float* f = F + (size_t)batch * NCH * NPIX;

    Row3f a0 = load3(a, y0 - 1, x), a1 = load3(a, y0, x), a2;
    Row3f b0 = load3(b, y0 - 1, x), b1 = load3(b, y0, x), b2;
    Row3f f0 = load3(f, y0 - 1, x), f1 = load3(f, y0, x), f2;

    double loss = 0.0;
    for (int i = 0; i < 32; ++i) {
        const int y = y0 + i;
        a2 = load3(a, y + 1, x);
        b2 = load3(b, y + 1, x);
        f2 = load3(f, y + 1, x);
        const float gA = sobel_g(a0, a1, a2);
        const float gB = sobel_g(b0, b1, b2);
        const float gF = sobel_g(f0, f1, f2);
        atomicAdd(&hc[__float_as_uint(gA) >> SH1], 1u);
        atomicAdd(&hc[BINS1 + (__float_as_uint(gB) >> SH1)], 1u);
        loss += (double)fabsf(gF - fmaxf(gA, gB));
        a0 = a1; a1 = a2;
        b0 = b1; b1 = b2;
        f0 = f1; f1 = f2;
    }
    __syncthreads();

    unsigned short* oA = hist1p + ((size_t)batch            * SEGS + seg) * BINS1;
    unsigned short* oB = hist1p + ((size_t)(NBATCH + batch) * SEGS + seg) * BINS1;
    for (int i = t; i < 2 * BINS1; i += 512) {          // sum copies; counts <= 16384 -> u16
        const unsigned v = h[i] + h[2 * BINS1 + i];
        if (i < BINS1) oA[i] = (unsigned short)v;
        else           oB[i - BINS1] = (unsigned short)v;
    }

    for (int off = 32; off > 0; off >>= 1) loss += __shfl_down(loss, off);
    if ((t & 63) == 0) lsum[t >> 6] = loss;
    __syncthreads();
    if (t == 0) {
        double s = 0.0;
        for (int i = 0; i < 8; ++i) s += lsum[i];
        atomicAdd(lossAcc, s);
    }
}

// ---------------- scan1a: reduce per-seg hists ----------------
extern "C" __global__ __launch_bounds__(256)
void k_scan1a(const unsigned short* __restrict__ hist1p, unsigned int* __restrict__ hist1r)
{
    const int idx = blockIdx.x * 256 + threadIdx.x;     // 65536 = 16 * 4096
    const int ib  = idx >> 12;
    const int bin = idx & (BINS1 - 1);
    const unsigned short* p = hist1p + (size_t)ib * SEGS * BINS1 + bin;
    unsigned int s = 0;
    #pragma unroll 8
    for (int sg = 0; sg < SEGS; ++sg) s += p[(size_t)sg * BINS1];
    hist1r[idx] = s;
}

// ---------------- scan1b: parallel rank-select of level-1 bin ----------------
extern "C" __global__ __launch_bounds__(1024)
void k_scan1b(const unsigned int* __restrict__ hist1r, const int* __restrict__ kptr,
              int* __restrict__ sel1, int* __restrict__ resid1)
{
    const int ib = blockIdx.x, t = threadIdx.x;
    const unsigned int* hr = hist1r + (size_t)ib * BINS1;
    long long kl = (long long)kptr[0];
    if (kl < 1 || kl > (long long)NPIX) {               // defensive: scalar sent as f32?
        float kf = ((const float*)kptr)[0];
        kl = (long long)kf;
        if (kl < 1) kl = 1;
        if (kl > NPIX) kl = NPIX;
    }
    const unsigned k = (unsigned)kl;

    const uint4 c = ((const uint4*)hr)[t];              // bins 4t..4t+3 (16B aligned)
    const unsigned s = c.x + c.y + c.z + c.w;
    __shared__ unsigned ls[1024];
    ls[t] = s; __syncthreads();
    for (int off = 1; off < 1024; off <<= 1) {
        unsigned v = (t >= off) ? ls[t - off] : 0u;
        __syncthreads();
        ls[t] += v;
        __syncthreads();
    }
    const unsigned incl = ls[t];
    const unsigned excl = incl - s;
    if (excl < k && k <= incl) {                        // unique winner thread
        unsigned cum = excl; int bin = t * 4;
        if (cum + c.x < k) { cum += c.x; ++bin;
          if (cum + c.y < k) { cum += c.y; ++bin;
            if (cum + c.z < k) { cum += c.z; ++bin; } } }
        sel1[ib] = bin;
        resid1[ib] = (int)(k - cum);
    }
}

// ---------------- pass B: masks + boundary-pixel candidate lists ----------------
#define PB_ROWS 32
extern "C" __global__ __launch_bounds__(1024)
void k_passB(const float* __restrict__ A, const float* __restrict__ B,
             const int* __restrict__ sel1, unsigned int* __restrict__ gCnt,
             uint2* __restrict__ list, unsigned cap, float* __restrict__ out)
{
    const int t = threadIdx.x;
    const int blk = blockIdx.x;                         // 256 = 8 batches * 32 bands
    const int batch = blk >> 5;
    const int y0 = (blk & 31) * PB_ROWS;
    const int x = t;

    const float* a = A + (size_t)batch * NCH * NPIX;
    const float* b = B + (size_t)batch * NCH * NPIX;
    const unsigned sA = (unsigned)sel1[batch];
    const unsigned sB = (unsigned)sel1[NBATCH + batch];
    float* mA = out + 1 + (size_t)batch * NPIX;
    float* mB = out + 1 + (size_t)NTOT + (size_t)batch * NPIX;

    __shared__ uint2 bufA[2048], bufB[2048];            // 32 KB staging
    __shared__ unsigned cntA, cntB, baseA, baseB;
    if (t == 0) { cntA = 0u; cntB = 0u; }
    __syncthreads();

    Row3f a0 = load3(a, y0 - 1, x), a1 = load3(a, y0, x), a2;
    Row3f b0 = load3(b, y0 - 1, x), b1 = load3(b, y0, x), b2;
    for (int i = 0; i < PB_ROWS; ++i) {
        const int y = y0 + i;
        a2 = load3(a, y + 1, x);
        b2 = load3(b, y + 1, x);
        const unsigned uA = __float_as_uint(sobel_g(a0, a1, a2));
        const unsigned uB = __float_as_uint(sobel_g(b0, b1, b2));
        const unsigned binA = uA >> SH1, binB = uB >> SH1;
        const unsigned idx = (unsigned)y * IMG_W + (unsigned)x;
        mA[idx] = (binA > sA) ? 1.0f : 0.0f;            // boundary bin: provisional 0, fixed later
        mB[idx] = (binB > sB) ? 1.0f : 0.0f;
        if (binA == sA) { unsigned p = atomicAdd(&cntA, 1u); bufA[p] = make_uint2(uA, idx); }
        if (binB == sB) { unsigned p = atomicAdd(&cntB, 1u); bufB[p] = make_uint2(uB, idx); }
        a0 = a1; a1 = a2;
        b0 = b1; b1 = b2;

        __syncthreads();                                // appends visible, counters stable
        const bool last = (i == PB_ROWS - 1);
        const unsigned nA = cntA, nB = cntB;            // uniform
        const bool doA = (nA >= 1024u) || (last && nA > 0u);
        const bool doB = (nB >= 1024u) || (last && nB > 0u);
        if (doA || doB) {
            if (t == 0) {
                if (doA) baseA = atomicAdd(&gCnt[batch], nA);
                if (doB) baseB = atomicAdd(&gCnt[NBATCH + batch], nB);
            }
            __syncthreads();
            if (doA) {
                const unsigned bs = baseA;
                for (unsigned j = t; j < nA; j += 1024u) {
                    const unsigned d = bs + j;
                    if (d < cap) list[(size_t)batch * cap + d] = bufA[j];
                }
            }
            if (doB) {
                const unsigned bs = baseB;
                for (unsigned j = t; j < nB; j += 1024u) {
                    const unsigned d = bs + j;
                    if (d < cap) list[(size_t)(NBATCH + batch) * cap + d] = bufB[j];
                }
            }
            __syncthreads();
            if (t == 0) { if (doA) cntA = 0u; if (doB) cntB = 0u; }
        }
        __syncthreads();
    }
}

// ---------------- selectfix: 19-bit select within boundary bin + mask fix-up ----------------
extern "C" __global__ __launch_bounds__(1024)
void k_selectfix(const uint2* __restrict__ list, const unsigned int* __restrict__ gCnt,
                 unsigned cap, const int* __restrict__ sel1, const int* __restrict__ resid1,
                 const double* __restrict__ lossAcc, float* __restrict__ out)
{
    const int ib = blockIdx.x, t = threadIdx.x;         // 16 blocks: [A batches | B batches]
    const unsigned n = min(gCnt[ib], cap);
    const unsigned kk = (unsigned)resid1[ib];
    const uint2* L = list + (size_t)ib * cap;

    __shared__ unsigned h2[BINS1];                      // 16 KB, reused for h3
    __shared__ unsigned ls[1024];
    __shared__ unsigned bcast[4];
    if (t < 4) bcast[t] = 0u;
    for (int i = t; i < BINS1; i += 1024) h2[i] = 0u;
    __syncthreads();

    // level-2: hist of (bits>>7)&4095 (all entries share bits>>19 == sel1)
    for (unsigned j = t; j < n; j += 1024u) atomicAdd(&h2[(L[j].x >> 7) & 4095u], 1u);
    __syncthreads();

    const unsigned c0 = h2[4 * t], c1 = h2[4 * t + 1], c2 = h2[4 * t + 2], c3 = h2[4 * t + 3];
    const unsigned s = c0 + c1 + c2 + c3;
    ls[t] = s; __syncthreads();
    for (int off = 1; off < 1024; off <<= 1) {
        unsigned v = (t >= off) ? ls[t - off] : 0u;
        __syncthreads();
        ls[t] += v;
        __syncthreads();
    }
    {
        const unsigned incl = ls[t], excl = incl - s;
        if (excl < kk && kk <= incl) {
            unsigned cum = excl; unsigned bin = 4u * t;
            if (cum + c0 < kk) { cum += c0; ++bin;
              if (cum + c1 < kk) { cum += c1; ++bin;
                if (cum + c2 < kk) { cum += c2; ++bin; } } }
            bcast[0] = bin;
            bcast[1] = kk - cum;
        }
    }
    __syncthreads();
    const unsigned sel2 = bcast[0], k3 = bcast[1];

    // level-3: hist of bits&127 among entries matching sel2
    if (t < 128) h2[t] = 0u;
    __syncthreads();
    for (unsigned j = t; j < n; j += 1024u) {
        const unsigned b = L[j].x;
        if (((b >> 7) & 4095u) == sel2) atomicAdd(&h2[b & 127u], 1u);
    }
    __syncthreads();
    {
        const unsigned s3 = (t < 128) ? h2[t] : 0u;
        ls[t] = s3; __syncthreads();
        for (int off = 1; off < 1024; off <<= 1) {
            unsigned v = (t >= off) ? ls[t - off] : 0u;
            __syncthreads();
            ls[t] += v;
            __syncthreads();
        }
        const unsigned incl = ls[t], excl = incl - s3;
        if (t < 128 && excl < k3 && k3 <= incl) {
            bcast[2] = ((unsigned)sel1[ib] << SH1) | (sel2 << 7) | (unsigned)t;
        }
    }
    __syncthreads();
    const unsigned kth = bcast[2];

    // fix-up: rewrite only boundary-bin pixels
    float* m = out + 1 + (size_t)ib * NPIX;             // [A(0..7) | B(8..15)] contiguous
    for (unsigned j = t; j < n; j += 1024u) {
        const uint2 e = L[j];
        m[e.y] = (e.x >= kth) ? 1.0f : 0.0f;
    }
    if (ib == 0 && t == 0) out[0] = (float)(lossAcc[0] * (1.0 / 8388608.0));
}

extern "C" void kernel_launch(void* const* d_in, const int* in_sizes, int n_in,
                              void* d_out, int out_size, void* d_ws, size_t ws_size,
                              hipStream_t stream)
{
    const float* A = (const float*)d_in[0];
    const float* B = (const float*)d_in[1];
    const float* F = (const float*)d_in[2];
    const int* kptr = (const int*)d_in[3];
    float* out = (float*)d_out;

    if (ws_size < (size_t)WS_LIST_OFF + 16 * 8 * 1024) return;  // need hist area + some list space

    char* ws = (char*)d_ws;
    double* lossAcc        = (double*)(ws + WS_MISC_OFF);
    unsigned int* gCnt     = (unsigned int*)(ws + WS_MISC_OFF + 64);
    unsigned int* hist1r   = (unsigned int*)(ws + WS_H1R_OFF);
    unsigned short* hist1p = (unsigned short*)(ws + WS_H1P_OFF);
    uint2* list            = (uint2*)(ws + WS_LIST_OFF);
    int* sel1              = (int*)(ws + WS_MISC_OFF + 128);
    int* resid1            = (int*)(ws + WS_MISC_OFF + 256);

    unsigned long long capll = (ws_size - WS_LIST_OFF) / (16ull * 8ull);
    unsigned cap = (capll > (unsigned long long)NPIX) ? (unsigned)NPIX : (unsigned)capll;

    hipMemsetAsync(ws, 0, WS_MISC_BYTES, stream);       // lossAcc + gCnt zeroed

    k_pass0    <<<dim3(NBATCH * SEGS), dim3(512), 0, stream>>>(A, B, F, hist1p, lossAcc);
    k_scan1a   <<<dim3(2 * NBATCH * BINS1 / 256), dim3(256), 0, stream>>>(hist1p, hist1r);
    k_scan1b   <<<dim3(2 * NBATCH), dim3(1024), 0, stream>>>(hist1r, kptr, sel1, resid1);
    k_passB    <<<dim3(NBATCH * 32), dim3(1024), 0, stream>>>(A, B, sel1, gCnt, list, cap, out);
    k_selectfix<<<dim3(2 * NBATCH), dim3(1024), 0, stream>>>(list, gCnt, cap, sel1, resid1, lossAcc, out);
}